// Round 3
// baseline (188.192 us; speedup 1.0000x reference)
//
#include <hip/hip_runtime.h>

#define NB   2048
#define SEQ  200
#define DIM  64
#define NH1  64
#define NH2  16
#define EPSF 1e-9f

typedef float fvec4 __attribute__((ext_vector_type(4)));
typedef short svec8 __attribute__((ext_vector_type(8)));   // 8 bf16 = 4 VGPRs

// LDS plan (bytes):
//   [0,16384)      setup: wc_t[d][h] fp32    | main: h1t per-wave 2 KB regions (first 8 KB)
//   [16384,17408)  setup: qpart[4][64]       | end: outp[4][64]
//   [17408,17664)  qall[64]
//   [17664,17920)  wsh[4][16]
#define SMEM_BYTES 17920

__device__ __forceinline__ short f2bf(float f) {
    unsigned u = __float_as_uint(f);
    u += 0x7fffu + ((u >> 16) & 1u);      // round-to-nearest-even
    return (short)(u >> 16);
}

__global__ __launch_bounds__(256, 4)
void din_attn_kernel(const float* __restrict__ q,        // [B,64]
                     const float* __restrict__ key,      // [B,200,64]
                     const int*   __restrict__ seqlen,   // [B,1]
                     const float* __restrict__ W1,       // [256,64]
                     const float* __restrict__ alpha1v,
                     const float* __restrict__ mean1v,
                     const float* __restrict__ var1v,
                     const float* __restrict__ W2,       // [64,16]
                     const float* __restrict__ alpha2v,
                     const float* __restrict__ mean2v,
                     const float* __restrict__ var2v,
                     const float* __restrict__ W3,       // [16]
                     float* __restrict__ out)            // [B,64]
{
    __shared__ __align__(16) char smem[SMEM_BYTES];
    float* wc_t  = (float*)(smem);                 // setup only
    float* qpart = (float*)(smem + 16384);
    float* outp  = (float*)(smem + 16384);         // end-of-kernel alias
    float* qall  = (float*)(smem + 17408);
    float* wshb  = (float*)(smem + 17664);

    const int b    = blockIdx.x;
    const int t    = threadIdx.x;
    const int lane = t & 63;
    const int wave = __builtin_amdgcn_readfirstlane(t >> 6);
    const int qd4  = lane >> 4;     // quad group 0..3
    const int m    = lane & 15;

    short* h1w = (short*)(smem + wave * 2048);     // per-wave 16x64 bf16 tile
    float* wsw = wshb + wave * 16;                 // per-wave weights

    const float* qrow = q + (size_t)b * DIM;
    int nseq = seqlen[b];
    nseq = nseq < SEQ ? nseq : SEQ;

    // ---- setup 1: wc_t[d][h] = (W1b - W1c) + q[d]*W1d ; qterm partials
    {
        const int h = lane;
        float qt = 0.f;
        #pragma unroll
        for (int i = 0; i < 16; ++i) {
            const int d = wave * 16 + i;           // uniform
            const float qdv  = qrow[d];            // -> sgpr
            const float w1a  = W1[(d)       * NH1 + h];
            const float w1b  = W1[(64 + d)  * NH1 + h];
            const float w1c  = W1[(128 + d) * NH1 + h];
            const float w1dd = W1[(192 + d) * NH1 + h];
            wc_t[d * NH1 + h] = (w1b - w1c) + qdv * w1dd;
            qt = fmaf(qdv, w1a + w1c, qt);
        }
        qpart[wave * 64 + h] = qt;
    }
    __syncthreads();

    // ---- setup 2: qterm reduce; B-fragments to registers; dice params
    if (t < 64)
        qall[t] = (qpart[t] + qpart[64 + t]) + (qpart[128 + t] + qpart[192 + t]);

    svec8 wcf[4][2];   // Wc B-frags: [colblock c][kstep kk]
    #pragma unroll
    for (int c = 0; c < 4; ++c)
        #pragma unroll
        for (int kk = 0; kk < 2; ++kk) {
            svec8 f;
            #pragma unroll
            for (int j = 0; j < 8; ++j) {
                const int d = kk * 32 + qd4 * 8 + j;
                f[j] = f2bf(wc_t[d * NH1 + (c * 16 + m)]);
            }
            wcf[c][kk] = f;
        }

    svec8 w2f[2];      // W2 B-frags
    #pragma unroll
    for (int kk = 0; kk < 2; ++kk) {
        svec8 f;
        #pragma unroll
        for (int j = 0; j < 8; ++j) {
            const int h = kk * 32 + qd4 * 8 + j;
            f[j] = f2bf(W2[h * NH2 + m]);
        }
        w2f[kk] = f;
    }

    float a1v[4], m1v[4], r1v[4];   // dice1 params for h = c*16 + m
    #pragma unroll
    for (int c = 0; c < 4; ++c) {
        a1v[c] = alpha1v[c * 16 + m];
        m1v[c] = mean1v[c * 16 + m];
        r1v[c] = rsqrtf(var1v[c * 16 + m] + EPSF);
    }
    const float a2s = alpha2v[m];   // dice2 params for j = m
    const float m2s = mean2v[m];
    const float r2s = rsqrtf(var2v[m] + EPSF);
    const float w3s = W3[m];

    __syncthreads();   // wc_t/qpart free; qall ready

    float qtermv[4];
    #pragma unroll
    for (int c = 0; c < 4; ++c) qtermv[c] = qall[c * 16 + m];

    fvec4 oacc0 = {0.f,0.f,0.f,0.f}, oacc1 = {0.f,0.f,0.f,0.f};
    fvec4 oacc2 = {0.f,0.f,0.f,0.f}, oacc3 = {0.f,0.f,0.f,0.f};

    // ---- main loop: each wave owns 16-row tiles end-to-end, no barriers
    const int ntiles = (nseq + 15) >> 4;
    for (int tile = wave; tile < ntiles; tile += 4) {
        // A-frag loads straight from global: lane = (row m, col group qd4)
        const int row  = tile * 16 + m;
        const int grow = row < SEQ ? row : SEQ - 1;          // clamp; masked by w=0
        const float* kp = key + ((size_t)b * SEQ + grow) * DIM + qd4 * 8;
        const fvec4 kv0 = *(const fvec4*)(kp);
        const fvec4 kv1 = *(const fvec4*)(kp + 4);
        const fvec4 kv2 = *(const fvec4*)(kp + 32);
        const fvec4 kv3 = *(const fvec4*)(kp + 36);

        svec8 af0, af1;
        #pragma unroll
        for (int j = 0; j < 4; ++j) {
            af0[j]     = f2bf(kv0[j]);
            af0[4 + j] = f2bf(kv1[j]);
            af1[j]     = f2bf(kv2[j]);
            af1[4 + j] = f2bf(kv3[j]);
        }

        // phase 1: x[16][64] = k @ Wc
        fvec4 acc[4];
        #pragma unroll
        for (int c = 0; c < 4; ++c) {
            acc[c] = (fvec4){0.f, 0.f, 0.f, 0.f};
            acc[c] = __builtin_amdgcn_mfma_f32_16x16x32_bf16(af0, wcf[c][0], acc[c], 0, 0, 0);
            acc[c] = __builtin_amdgcn_mfma_f32_16x16x32_bf16(af1, wcf[c][1], acc[c], 0, 0, 0);
        }

        // dice1; write h1 bf16 to per-wave LDS [row][h] (row-major, 128 B rows)
        #pragma unroll
        for (int c = 0; c < 4; ++c) {
            #pragma unroll
            for (int reg = 0; reg < 4; ++reg) {
                const float x  = acc[c][reg] + qtermv[c];
                const float xn = (x - m1v[c]) * r1v[c];
                const float p  = 1.f / (1.f + __expf(-xn));
                const float h1 = x * (a1v[c] + p * (1.f - a1v[c]));
                h1w[(qd4 * 4 + reg) * NH1 + c * 16 + m] = f2bf(h1);
            }
        }
        // same-wave LDS write->read; compiler inserts lgkmcnt wait

        // phase 2: h2[16][16] = h1 @ W2 ; dice2 ; score ; weights
        const svec8 b0 = *(const svec8*)(h1w + m * NH1 + qd4 * 8);
        const svec8 b1 = *(const svec8*)(h1w + m * NH1 + 32 + qd4 * 8);
        fvec4 acc2 = (fvec4){0.f, 0.f, 0.f, 0.f};
        acc2 = __builtin_amdgcn_mfma_f32_16x16x32_bf16(b0, w2f[0], acc2, 0, 0, 0);
        acc2 = __builtin_amdgcn_mfma_f32_16x16x32_bf16(b1, w2f[1], acc2, 0, 0, 0);

        #pragma unroll
        for (int reg = 0; reg < 4; ++reg) {
            const float x  = acc2[reg];                 // h2[qd4*4+reg][j=m]
            const float xn = (x - m2s) * r2s;
            const float p  = 1.f / (1.f + __expf(-xn));
            const float hd = x * (a2s + p * (1.f - a2s));
            float s = hd * w3s;
            s += __shfl_xor(s, 1);
            s += __shfl_xor(s, 2);
            s += __shfl_xor(s, 4);
            s += __shfl_xor(s, 8);                      // sum over 16 j-lanes
            if (m == 0) {
                const int rg = tile * 16 + qd4 * 4 + reg;
                wsw[qd4 * 4 + reg] = (rg < nseq) ? 1.f / (1.f + __expf(-s)) : 0.f;
            }
        }
        // same-wave LDS write->read

        // phase 3: weighted sum from the fp32 regs already in hand
        const float w = wsw[m];                         // weight of this lane's row
        oacc0 += w * kv0;
        oacc1 += w * kv1;
        oacc2 += w * kv2;
        oacc3 += w * kv3;
    }

    // ---- reduce oacc over the 16 m-lanes (they share a column set)
    #pragma unroll
    for (int e = 0; e < 4; ++e) {
        float v0 = oacc0[e], v1 = oacc1[e], v2 = oacc2[e], v3 = oacc3[e];
        #pragma unroll
        for (int msk = 1; msk < 16; msk <<= 1) {
            v0 += __shfl_xor(v0, msk);
            v1 += __shfl_xor(v1, msk);
            v2 += __shfl_xor(v2, msk);
            v3 += __shfl_xor(v3, msk);
        }
        oacc0[e] = v0; oacc1[e] = v1; oacc2[e] = v2; oacc3[e] = v3;
    }
    if (m == 0) {
        #pragma unroll
        for (int e = 0; e < 4; ++e) {
            outp[wave * 64 + qd4 * 8 + e]          = oacc0[e];
            outp[wave * 64 + qd4 * 8 + 4 + e]      = oacc1[e];
            outp[wave * 64 + 32 + qd4 * 8 + e]     = oacc2[e];
            outp[wave * 64 + 32 + qd4 * 8 + 4 + e] = oacc3[e];
        }
    }
    __syncthreads();

    if (t < 64) {
        out[(size_t)b * DIM + t] = (outp[t] + outp[64 + t]) +
                                   (outp[128 + t] + outp[192 + t]);
    }
}

extern "C" void kernel_launch(void* const* d_in, const int* in_sizes, int n_in,
                              void* d_out, int out_size, void* d_ws, size_t ws_size,
                              hipStream_t stream) {
    const float* q      = (const float*)d_in[0];
    const float* key    = (const float*)d_in[1];
    const int*   seqlen = (const int*)d_in[2];
    const float* W1     = (const float*)d_in[3];
    const float* alpha1 = (const float*)d_in[4];
    const float* mean1  = (const float*)d_in[5];
    const float* var1   = (const float*)d_in[6];
    const float* W2     = (const float*)d_in[7];
    const float* alpha2 = (const float*)d_in[8];
    const float* mean2  = (const float*)d_in[9];
    const float* var2   = (const float*)d_in[10];
    const float* W3     = (const float*)d_in[11];
    float* out          = (float*)d_out;

    din_attn_kernel<<<NB, 256, 0, stream>>>(q, key, seqlen, W1,
                                            alpha1, mean1, var1,
                                            W2, alpha2, mean2, var2,
                                            W3, out);
}